// Round 2
// baseline (160.741 us; speedup 1.0000x reference)
//
#include <hip/hip_runtime.h>
#include <hip/hip_bf16.h>

// BERT self-attention, B=8 S=1024 D=768 H=12 DH=64, fp32 in/out.
// (1) bf16 MFMA projection GEMM -> mixed (bf16, ws)
// (2) flash-style fused attention, Q=K=V=mixed, 128 q-rows/block,
//     swizzled stride-64 LDS tiles, static-index transpose scatter.

#define D_MODEL 768
#define SEQ     1024
#define NHEAD   12
#define DHEAD   64
#define BATCH   8
#define QB      128
#define LOG2E   1.44269504088896f

typedef __attribute__((ext_vector_type(8))) short bf16x8;
typedef __attribute__((ext_vector_type(4))) short bf16x4v;
typedef __attribute__((ext_vector_type(4))) float f32x4;

__device__ __forceinline__ unsigned short f2bf(float f) {
  __hip_bfloat16 h = __float2bfloat16(f);
  return *reinterpret_cast<unsigned short*>(&h);
}

__device__ __forceinline__ float fexp2(float x) {
#if __has_builtin(__builtin_amdgcn_exp2f)
  return __builtin_amdgcn_exp2f(x);
#else
  return exp2f(x);
#endif
}

// row-major [r][c] tile, 64 elems/row, 16B granules rotated by row
__device__ __forceinline__ int swz(int r, int c) {
  return (r << 6) + ((((c >> 3) + r) & 7) << 3) + (c & 7);
}
// transposed tile XT[d][t], granules rotated by d>>3 (write-side spread)
__device__ __forceinline__ int swzT(int d, int t) {
  return (d << 6) + ((((t >> 3) + (d >> 3)) & 7) << 3) + (t & 7);
}

// ---------------------------------------------------------------------------
// Projection GEMM: mixed = bf16(X @ W^T + b).  M=8192 N=768 K=768.
// ---------------------------------------------------------------------------
__global__ __launch_bounds__(256) void proj_kernel(
    const float* __restrict__ X, const float* __restrict__ W,
    const float* __restrict__ bias, unsigned short* __restrict__ mixed)
{
  __shared__ unsigned short As[128][40];
  __shared__ unsigned short Bs[128][40];

  const int tid = threadIdx.x;
  const int l   = tid & 63;
  const int w   = tid >> 6;
  const int m0  = blockIdx.x * 128;
  const int n0  = blockIdx.y * 128;
  const int wm  = (w >> 1) * 64;
  const int wn  = (w & 1) * 64;
  const int lr  = l & 15;
  const int lk  = (l >> 4) * 8;

  f32x4 acc[4][4] = {};

  for (int k0 = 0; k0 < D_MODEL; k0 += 32) {
    #pragma unroll
    for (int rr = 0; rr < 4; ++rr) {
      int p   = tid + rr * 256;
      int row = p >> 3;
      int cg  = (p & 7) * 4;
      f32x4 a  = *(const f32x4*)&X[(size_t)(m0 + row) * D_MODEL + k0 + cg];
      f32x4 bv = *(const f32x4*)&W[(size_t)(n0 + row) * D_MODEL + k0 + cg];
      bf16x4v ap, bp;
      #pragma unroll
      for (int j = 0; j < 4; ++j) { ap[j] = (short)f2bf(a[j]); bp[j] = (short)f2bf(bv[j]); }
      *(bf16x4v*)&As[row][cg] = ap;
      *(bf16x4v*)&Bs[row][cg] = bp;
    }
    __syncthreads();

    bf16x8 af[4], bfr[4];
    #pragma unroll
    for (int am = 0; am < 4; ++am) af[am]  = *(const bf16x8*)&As[wm + am * 16 + lr][lk];
    #pragma unroll
    for (int bn = 0; bn < 4; ++bn) bfr[bn] = *(const bf16x8*)&Bs[wn + bn * 16 + lr][lk];

    #pragma unroll
    for (int am = 0; am < 4; ++am)
      #pragma unroll
      for (int bn = 0; bn < 4; ++bn)
        acc[am][bn] = __builtin_amdgcn_mfma_f32_16x16x32_bf16(
            af[am], bfr[bn], acc[am][bn], 0, 0, 0);
    __syncthreads();
  }

  const int orow = (l >> 4) * 4;
  #pragma unroll
  for (int bn = 0; bn < 4; ++bn) {
    int   col  = n0 + wn + bn * 16 + lr;
    float bcol = bias[col];
    #pragma unroll
    for (int am = 0; am < 4; ++am)
      #pragma unroll
      for (int i = 0; i < 4; ++i) {
        int row = m0 + wm + am * 16 + orow + i;
        mixed[(size_t)row * D_MODEL + col] = f2bf(acc[am][bn][i] + bcol);
      }
  }
}

// ---------------------------------------------------------------------------
// Fused attention: 128 q-rows/block, 4 waves x 32 rows (2 m-frags each).
// ---------------------------------------------------------------------------
__global__ __launch_bounds__(256) void attn_kernel(
    const unsigned short* __restrict__ mixed, const float* __restrict__ mask,
    float* __restrict__ out)
{
  __shared__ unsigned short Qs[QB * DHEAD];       // 16 KB, swz
  __shared__ unsigned short Xs[64 * DHEAD];       //  8 KB, swz
  __shared__ unsigned short XTs[DHEAD * 64];      //  8 KB, swzT
  __shared__ unsigned short Ps[4][32 * DHEAD];    // 16 KB, swz (per wave)

  const int tid = threadIdx.x;
  const int l   = tid & 63;
  const int w   = tid >> 6;
  const int q0  = blockIdx.x * QB;
  const int h   = blockIdx.y;
  const int b   = blockIdx.z;
  const int lr  = l & 15;
  const int g   = l >> 4;
  const int lk  = g * 8;
  const size_t base = ((size_t)b * SEQ) * D_MODEL + h * DHEAD;

  // ---- stage Q (128 x 64) ----
  #pragma unroll
  for (int rr = 0; rr < 4; ++rr) {
    int p = tid + rr * 256;
    int row = p >> 3, col = (p & 7) * 8;
    bf16x8 v = *(const bf16x8*)&mixed[base + (size_t)(q0 + row) * D_MODEL + col];
    *(bf16x8*)&Qs[swz(row, col)] = v;
  }
  __syncthreads();

  bf16x8 qf[2][2];
  #pragma unroll
  for (int mf = 0; mf < 2; ++mf)
    #pragma unroll
    for (int kf = 0; kf < 2; ++kf)
      qf[mf][kf] = *(const bf16x8*)&Qs[swz(w * 32 + mf * 16 + lr, kf * 32 + lk)];

  float m_i[2][4], l_i[2][4];
  f32x4 cacc[2][4] = {};
  #pragma unroll
  for (int mf = 0; mf < 2; ++mf)
    #pragma unroll
    for (int i = 0; i < 4; ++i) { m_i[mf][i] = -1e30f; l_i[mf][i] = 0.f; }

  const float SCL = 0.125f * LOG2E;

  for (int t0 = 0; t0 < SEQ; t0 += 64) {
    // mask for this tile's k-columns (pre-scaled to exp2 domain)
    float mk[4];
    #pragma unroll
    for (int nf = 0; nf < 4; ++nf)
      mk[nf] = mask[(size_t)b * SEQ + t0 + nf * 16 + lr] * LOG2E;

    // ---- stage X tile + static-index transpose ----
    #pragma unroll
    for (int rr = 0; rr < 2; ++rr) {
      int p = tid + rr * 256;
      int row = p >> 3, col = (p & 7) * 8;
      bf16x8 v = *(const bf16x8*)&mixed[base + (size_t)(t0 + row) * D_MODEL + col];
      *(bf16x8*)&Xs[swz(row, col)] = v;
      int c8 = col >> 3;
      int xb = (col << 6) + ((((row >> 3) + c8) & 7) << 3) + (row & 7);
      #pragma unroll
      for (int j = 0; j < 8; ++j)
        XTs[xb + (j << 6)] = (unsigned short)v[j];   // compile-time extract
    }
    __syncthreads();

    // ---- S = Q @ X^T ----
    f32x4 sacc[2][4] = {};
    #pragma unroll
    for (int kf = 0; kf < 2; ++kf)
      #pragma unroll
      for (int nf = 0; nf < 4; ++nf) {
        bf16x8 kfr = *(const bf16x8*)&Xs[swz(nf * 16 + lr, kf * 32 + lk)];
        sacc[0][nf] = __builtin_amdgcn_mfma_f32_16x16x32_bf16(
            qf[0][kf], kfr, sacc[0][nf], 0, 0, 0);
        sacc[1][nf] = __builtin_amdgcn_mfma_f32_16x16x32_bf16(
            qf[1][kf], kfr, sacc[1][nf], 0, 0, 0);
      }

    // ---- scale + mask (exp2 domain), online softmax ----
    #pragma unroll
    for (int mf = 0; mf < 2; ++mf)
      #pragma unroll
      for (int nf = 0; nf < 4; ++nf)
        #pragma unroll
        for (int i = 0; i < 4; ++i)
          sacc[mf][nf][i] = sacc[mf][nf][i] * SCL + mk[nf];

    #pragma unroll
    for (int mf = 0; mf < 2; ++mf)
      #pragma unroll
      for (int i = 0; i < 4; ++i) {
        float rm = fmaxf(fmaxf(sacc[mf][0][i], sacc[mf][1][i]),
                         fmaxf(sacc[mf][2][i], sacc[mf][3][i]));
        rm = fmaxf(rm, __shfl_xor(rm, 1));
        rm = fmaxf(rm, __shfl_xor(rm, 2));
        rm = fmaxf(rm, __shfl_xor(rm, 4));
        rm = fmaxf(rm, __shfl_xor(rm, 8));
        float mn = fmaxf(m_i[mf][i], rm);
        float al = fexp2(m_i[mf][i] - mn);
        float rs = 0.f;
        #pragma unroll
        for (int nf = 0; nf < 4; ++nf) {
          float pv = fexp2(sacc[mf][nf][i] - mn);
          sacc[mf][nf][i] = pv;
          rs += pv;
        }
        rs += __shfl_xor(rs, 1);
        rs += __shfl_xor(rs, 2);
        rs += __shfl_xor(rs, 4);
        rs += __shfl_xor(rs, 8);
        l_i[mf][i] = l_i[mf][i] * al + rs;
        m_i[mf][i] = mn;
        #pragma unroll
        for (int nf = 0; nf < 4; ++nf) cacc[mf][nf][i] *= al;
      }

    // ---- P -> per-wave LDS (no barrier needed: wave-private) ----
    const int pr = g * 4;
    #pragma unroll
    for (int mf = 0; mf < 2; ++mf)
      #pragma unroll
      for (int nf = 0; nf < 4; ++nf)
        #pragma unroll
        for (int i = 0; i < 4; ++i)
          Ps[w][swz(mf * 16 + pr + i, nf * 16 + lr)] = f2bf(sacc[mf][nf][i]);

    // ---- ctx += P @ X ----
    bf16x8 pa[2][2];
    #pragma unroll
    for (int mf = 0; mf < 2; ++mf)
      #pragma unroll
      for (int kf = 0; kf < 2; ++kf)
        pa[mf][kf] = *(const bf16x8*)&Ps[w][swz(mf * 16 + lr, kf * 32 + lk)];
    #pragma unroll
    for (int kf = 0; kf < 2; ++kf)
      #pragma unroll
      for (int nf = 0; nf < 4; ++nf) {
        bf16x8 vf = *(const bf16x8*)&XTs[swzT(nf * 16 + lr, kf * 32 + lk)];
        cacc[0][nf] = __builtin_amdgcn_mfma_f32_16x16x32_bf16(
            pa[0][kf], vf, cacc[0][nf], 0, 0, 0);
        cacc[1][nf] = __builtin_amdgcn_mfma_f32_16x16x32_bf16(
            pa[1][kf], vf, cacc[1][nf], 0, 0, 0);
      }
    __syncthreads();  // protect Xs/XTs before next tile's staging
  }

  // ---- normalize + store ----
  #pragma unroll
  for (int mf = 0; mf < 2; ++mf)
    #pragma unroll
    for (int nf = 0; nf < 4; ++nf)
      #pragma unroll
      for (int i = 0; i < 4; ++i) {
        int row = q0 + w * 32 + mf * 16 + g * 4 + i;
        int col = h * DHEAD + nf * 16 + lr;
        out[((size_t)b * SEQ + row) * D_MODEL + col] = cacc[mf][nf][i] / l_i[mf][i];
      }
}

// ---------------------------------------------------------------------------
extern "C" void kernel_launch(void* const* d_in, const int* in_sizes, int n_in,
                              void* d_out, int out_size, void* d_ws, size_t ws_size,
                              hipStream_t stream) {
  const float* x    = (const float*)d_in[0];
  const float* mask = (const float*)d_in[1];
  const float* W    = (const float*)d_in[2];
  const float* bias = (const float*)d_in[3];
  float* out        = (float*)d_out;

  unsigned short* mixed = (unsigned short*)d_ws;  // [8192][768] bf16 = 12.6 MB

  dim3 gp(8192 / 128, D_MODEL / 128);             // (64, 6)
  proj_kernel<<<gp, 256, 0, stream>>>(x, W, bias, mixed);

  dim3 ga(SEQ / QB, NHEAD, BATCH);                // (8, 12, 8)
  attn_kernel<<<ga, 256, 0, stream>>>(mixed, mask, out);
}